// Round 1
// baseline (2308.951 us; speedup 1.0000x reference)
//
#include <hip/hip_runtime.h>
#include <math.h>

// Problem constants (B=2, H=16, L=2048, D=64)
#define LSEQ 2048
#define DH   64
#define NBH  32      // B*H
#define TQ   16      // q rows per block
#define TK   64      // k columns per tile
#define NT   32      // LSEQ / TK
#define NW   8       // waves per block
#define RPW  2       // q rows per wave
#define KSTR 68      // LDS row stride in floats (16B aligned: 68*4=272)

// out tensor elements (output part of d_out), weights follow
#define OUT_ELEMS (NBH * LSEQ * DH)

__launch_bounds__(512, 2)
__global__ void attn_fp32_kernel(const float* __restrict__ qg,
                                 const float* __restrict__ kg,
                                 const float* __restrict__ vg,
                                 const float* __restrict__ bias,
                                 float* __restrict__ outg,   // [NBH][LSEQ][DH]
                                 float* __restrict__ wg) {   // [NBH][LSEQ][LSEQ]
  const int bh   = blockIdx.y;
  const int qt   = blockIdx.x;
  const int tid  = threadIdx.x;
  const int wave = tid >> 6;
  const int lane = tid & 63;

  __shared__ float q_lds[TQ][DH];        // 4 KB
  __shared__ float kv_lds[TK][KSTR];     // 17.4 KB
  __shared__ float w_lds[NW][RPW][TK];   // 4 KB

  const int q0 = qt * TQ;
  const long long kv_base = (long long)bh * LSEQ * DH;           // head base for k/v/q/out
  const long long q_base  = kv_base + (long long)q0 * DH;

  // ---- stage Q tile: 16*64 = 1024 floats = 256 float4 ----
  if (tid < 256) {
    ((float4*)q_lds)[tid] = ((const float4*)(qg + q_base))[tid];
  }
  __syncthreads();

  const float scale = 0.125f;  // 1/sqrt(64)
  const int r0 = wave * RPW;
  const long long brow0 = ((long long)bh * LSEQ + (q0 + r0)) * LSEQ;  // bias/weights row base

  float sreg[RPW][NT];

  // ================= Phase 1: scores = scale*QK^T + bias =================
#pragma unroll
  for (int kt = 0; kt < NT; ++kt) {
    // stage K tile: 64 rows x 64 floats = 1024 float4, 512 threads x 2
    {
      const float4* src = (const float4*)(kg + kv_base + (long long)kt * TK * DH);
#pragma unroll
      for (int it = 0; it < 2; ++it) {
        int f  = tid + it * 512;
        int kk = f >> 4, d4 = f & 15;
        *(float4*)&kv_lds[kk][d4 * 4] = src[f];
      }
    }
    __syncthreads();

    float s0 = 0.f, s1 = 0.f;
#pragma unroll
    for (int d4 = 0; d4 < 16; ++d4) {
      float4 kv = *(const float4*)&kv_lds[lane][d4 * 4];   // lane j = k row j
      float4 qa = *(const float4*)&q_lds[r0 + 0][d4 * 4];  // broadcast
      float4 qb = *(const float4*)&q_lds[r0 + 1][d4 * 4];  // broadcast
      s0 += qa.x * kv.x; s0 += qa.y * kv.y; s0 += qa.z * kv.z; s0 += qa.w * kv.w;
      s1 += qb.x * kv.x; s1 += qb.y * kv.y; s1 += qb.z * kv.z; s1 += qb.w * kv.w;
    }
    float b0 = bias[brow0 + 0 * LSEQ + kt * TK + lane];
    float b1 = bias[brow0 + 1 * LSEQ + kt * TK + lane];
    sreg[0][kt] = s0 * scale + b0;
    sreg[1][kt] = s1 * scale + b1;
    __syncthreads();
  }

  // ================= Phase 2: softmax over 2048 (32 regs x 64 lanes) =================
  float acc[RPW];
#pragma unroll
  for (int r = 0; r < RPW; ++r) {
    float m = -1e30f;
#pragma unroll
    for (int kt = 0; kt < NT; ++kt) m = fmaxf(m, sreg[r][kt]);
#pragma unroll
    for (int off = 32; off >= 1; off >>= 1) m = fmaxf(m, __shfl_xor(m, off));
    float l = 0.f;
#pragma unroll
    for (int kt = 0; kt < NT; ++kt) {
      float p = __expf(sreg[r][kt] - m);
      sreg[r][kt] = p;
      l += p;
    }
#pragma unroll
    for (int off = 32; off >= 1; off >>= 1) l += __shfl_xor(l, off);
    float inv = 1.f / l;
#pragma unroll
    for (int kt = 0; kt < NT; ++kt) sreg[r][kt] *= inv;
    acc[r] = 0.f;
  }

  // ================= Phase 3: write weights + PV =================
#pragma unroll
  for (int kt = 0; kt < NT; ++kt) {
    // stage V tile
    {
      const float4* src = (const float4*)(vg + kv_base + (long long)kt * TK * DH);
#pragma unroll
      for (int it = 0; it < 2; ++it) {
        int f  = tid + it * 512;
        int kk = f >> 4, d4 = f & 15;
        *(float4*)&kv_lds[kk][d4 * 4] = src[f];
      }
    }
    // weights out (coalesced) + per-wave LDS strip for broadcast in PV
#pragma unroll
    for (int r = 0; r < RPW; ++r) {
      float w = sreg[r][kt];
      wg[brow0 + (long long)r * LSEQ + kt * TK + lane] = w;
      w_lds[wave][r][lane] = w;
    }
    __syncthreads();   // covers both V staging and w_lds strips

    // PV: lane = d; acc[r] += sum_k w[r][k] * V[k][d]
#pragma unroll
    for (int k4 = 0; k4 < 16; ++k4) {
      float4 w0 = *(const float4*)&w_lds[wave][0][k4 * 4];  // broadcast
      float4 w1 = *(const float4*)&w_lds[wave][1][k4 * 4];  // broadcast
      const float* wp0 = (const float*)&w0;
      const float* wp1 = (const float*)&w1;
#pragma unroll
      for (int c = 0; c < 4; ++c) {
        float vv = kv_lds[k4 * 4 + c][lane];   // conflict-free: bank = (4k+c)*4+lane mod 32
        acc[0] += wp0[c] * vv;
        acc[1] += wp1[c] * vv;
      }
    }
    __syncthreads();
  }

  // ---- epilogue: output rows (coalesced, lane = d) ----
#pragma unroll
  for (int r = 0; r < RPW; ++r) {
    outg[kv_base + (long long)(q0 + r0 + r) * DH + lane] = acc[r];
  }
}

extern "C" void kernel_launch(void* const* d_in, const int* in_sizes, int n_in,
                              void* d_out, int out_size, void* d_ws, size_t ws_size,
                              hipStream_t stream) {
  const float* q    = (const float*)d_in[0];
  const float* k    = (const float*)d_in[1];
  const float* v    = (const float*)d_in[2];
  const float* bias = (const float*)d_in[3];
  float* out = (float*)d_out;                 // [2,16,2048,64]
  float* w   = (float*)d_out + OUT_ELEMS;     // [2,16,2048,2048]

  dim3 grid(LSEQ / TQ, NBH);   // (128, 32)
  dim3 block(512);
  attn_fp32_kernel<<<grid, block, 0, stream>>>(q, k, v, bias, out, w);
}